// Round 15
// baseline (139.915 us; speedup 1.0000x reference)
//
#include <hip/hip_runtime.h>

// ---------------------------------------------------------------------------
// Fused attention block: qkv = x@Wqkv+b; per-head softmax(q k^T/8 + keybias) v;
// out = attn@Wproj+b.  B=4 N=2048 C=768 H=12 HD=64.
// Internal compute bf16 MFMA (16x16x32), fp32 accumulate.
// R15: (1) attn — per-tile s-zeroing eliminated via loop-invariant zero C-in
// on the peeled kkk=0 MFMAs (removes ~32 v_mov/wave/tile from the VALU pipe);
// (2) GEMMs — T1 XCD-aware swizzle, bm-major ownership (each XCD's L2 keeps
// its 8 A-panels resident across all 24/12 bn re-uses). Else R14 verbatim.
// ---------------------------------------------------------------------------

typedef short short8 __attribute__((ext_vector_type(8)));
typedef float f32x4 __attribute__((ext_vector_type(4)));
typedef unsigned int u32x4 __attribute__((ext_vector_type(4)));

#define GLB_AS(p) ((const __attribute__((address_space(1))) void*)(p))
#define LDS_AS(p) ((__attribute__((address_space(3))) void*)(p))

__device__ __forceinline__ void gload_lds16(const void* g, void* l) {
  // dest = wave-uniform LDS base + lane*16 (m97 fast path)
  __builtin_amdgcn_global_load_lds(GLB_AS(g), LDS_AS(l), 16, 0, 0);
}

__device__ __forceinline__ f32x4 mfma16(short8 a, short8 b, f32x4 c) {
  return __builtin_amdgcn_mfma_f32_16x16x32_bf16(a, b, c, 0, 0, 0);
}

__device__ __forceinline__ unsigned short f2bf(float f) {
  union { float f; unsigned u; } v; v.f = f;
  unsigned r = v.u + 0x7fffu + ((v.u >> 16) & 1u);
  return (unsigned short)(r >> 16);
}

__device__ __forceinline__ float bf2f(unsigned short u) {
  union { unsigned u; float f; } v; v.u = ((unsigned)u) << 16;
  return v.f;
}

// packed f32x2 -> bf16x2 (lo = a, hi = b)
__device__ __forceinline__ unsigned cvt_pk_bf16(float a, float b) {
  unsigned r;
  asm("v_cvt_pk_bf16_f32 %0, %1, %2" : "=v"(r) : "v"(a), "v"(b));
  return r;
}

#define LOG2E 1.44269504088896340736f

// key-slot permutation: S^T slot m holds original key kappa1(m).
// kappa1(m) = 32*m4 + 8*((m>>2)&3) + 4*m5 + (m&3)  (bijective on 0..63)
__device__ __forceinline__ int kappa1(int m) {
  return ((m >> 4) & 1) * 32 + ((m >> 2) & 3) * 8 + ((m >> 5) & 1) * 4 + (m & 3);
}

// --------------------------- fused prep kernel ------------------------------
// blocks [0,3072):      x f32 -> bf16 (8 elems/thread)
// blocks [3072,3104):   ebb = bf16(exp(klb))
// blocks [3104,4832):   wqkv^T (f32 [768][2304] -> bf16 [2304][768])
// blocks [4832,5408):   wproj^T (f32 [768][768] -> bf16 [768][768])
__global__ __launch_bounds__(256) void prep(
    const float* __restrict__ x, unsigned short* __restrict__ xb,
    const float* __restrict__ klb, unsigned short* __restrict__ ebb,
    const float* __restrict__ wqkv, unsigned short* __restrict__ wqkvT,
    const float* __restrict__ wproj, unsigned short* __restrict__ wprojT) {
  const int bid = blockIdx.x, tid = threadIdx.x;
  if (bid < 3072) {
    int i = bid * 256 + tid;
    const float4* p = (const float4*)x + 2 * (size_t)i;
    float4 a = p[0], c = p[1];
    short8 r;
    r[0] = (short)f2bf(a.x); r[1] = (short)f2bf(a.y); r[2] = (short)f2bf(a.z); r[3] = (short)f2bf(a.w);
    r[4] = (short)f2bf(c.x); r[5] = (short)f2bf(c.y); r[6] = (short)f2bf(c.z); r[7] = (short)f2bf(c.w);
    ((short8*)xb)[i] = r;
    return;
  }
  if (bid < 3104) {
    int i = (bid - 3072) * 256 + tid;
    ebb[i] = f2bf(__builtin_exp2f(klb[i] * LOG2E));
    return;
  }
  // transpose+convert branches (block-uniform; LDS tile + barrier ok)
  __shared__ float t[32][33];
  const float* src;
  unsigned short* dst;
  int R, C, bx, by;
  if (bid < 4832) {
    int i = bid - 3104;
    src = wqkv; dst = wqkvT; R = 768; C = 2304; bx = i % 72; by = i / 72;
  } else {
    int i = bid - 4832;
    src = wproj; dst = wprojT; R = 768; C = 768; bx = i % 24; by = i / 24;
  }
  int tx = tid & 31, ty = tid >> 5;
  int c0 = bx * 32, r0 = by * 32;
#pragma unroll
  for (int i = 0; i < 32; i += 8)
    t[ty + i][tx] = src[(size_t)(r0 + ty + i) * C + c0 + tx];
  __syncthreads();
#pragma unroll
  for (int i = 0; i < 32; i += 8)
    dst[(size_t)(c0 + ty + i) * R + r0 + tx] = f2bf(t[tx][ty + i]);
}

// ------------------------------- GEMM --------------------------------------
// C[M,N] = A[M,K] * Bt[N,K]^T, 128xBN tile (BN = 32*BNF), BK=64, 4 waves (2x2),
// m97 structure, 3 blocks/CU. 1D grid + XCD-aware swizzle: each XCD owns a
// contiguous bm-range (A-panels L2-resident across all bn re-uses).
// EPI=0 (BNF=3, NBN=24): qkv epilogue — bn<16: Q (x0.125*log2e) / K scatter;
//        bn>=16: V transpose-through-LDS, write V^T*eb coalesced.
// EPI=1 (BNF=2, NBN=12): proj epilogue (bias, fp32 out [M][768])
template <int EPI, int BNF, int NBN>
__global__ __launch_bounds__(256, 3) void gemm_bt(
    const unsigned short* __restrict__ A, const unsigned short* __restrict__ Bt,
    const float* __restrict__ bias, float* __restrict__ outf,
    unsigned short* __restrict__ qo, unsigned short* __restrict__ ko,
    unsigned short* __restrict__ vo, const unsigned short* __restrict__ ebb,
    int K) {
  constexpr int BN = BNF * 32;
  __shared__ __align__(16) unsigned short smem[128 * 64 + BN * 64];
  unsigned short* As = smem;
  unsigned short* Bs = smem + 128 * 64;
  const int tid = threadIdx.x;
  const int lane = tid & 63, wid = tid >> 6;
  const int lr = lane & 15, lg = lane >> 4;
  // XCD swizzle (gridDim.x % 8 == 0): xcd w owns swz range [w*chunk,(w+1)*chunk)
  // decoded bm-major -> each XCD keeps its 8 A-panels in its private L2.
  const int wg = blockIdx.x;
  const int chunk = gridDim.x >> 3;
  const int swz = (wg & 7) * chunk + (wg >> 3);
  const int bm = swz / NBN, bn = swz - bm * NBN;
  const int wr = (wid >> 1) * 64, wc = (wid & 1) * (BNF * 16);

  const unsigned short* ap[4];
  unsigned aoff[4];
#pragma unroll
  for (int i = 0; i < 4; ++i) {
    int c = wid * 4 + i;
    int r = c * 8 + (lane >> 3);
    int gs = (lane & 7) ^ (r & 7);
    ap[i] = A + (size_t)(bm * 128 + r) * K + gs * 8;
    aoff[i] = (unsigned)c * 1024;
  }
  const unsigned short* bp[BNF];
  unsigned boff[BNF];
#pragma unroll
  for (int i = 0; i < BNF; ++i) {
    int c = wid * BNF + i;
    int r = c * 8 + (lane >> 3);
    int gs = (lane & 7) ^ (r & 7);
    bp[i] = Bt + (size_t)(bn * BN + r) * K + gs * 8;
    boff[i] = (unsigned)c * 1024;
  }

  f32x4 acc[4][BNF] = {};
  const int nt = K >> 6;
  for (int t = 0; t < nt; ++t) {
#pragma unroll
    for (int i = 0; i < 4; ++i) {
      gload_lds16(ap[i], (char*)As + aoff[i]);
      ap[i] += 64;
    }
#pragma unroll
    for (int i = 0; i < BNF; ++i) {
      gload_lds16(bp[i], (char*)Bs + boff[i]);
      bp[i] += 64;
    }
    __syncthreads();
#pragma unroll
    for (int kkk = 0; kkk < 2; ++kkk) {
      short8 af[4], bf[BNF];
#pragma unroll
      for (int mf = 0; mf < 4; ++mf) {
        int r = wr + mf * 16 + lr;
        int g = kkk * 4 + lg;
        af[mf] = *(const short8*)((const char*)As + r * 128 + ((g ^ (r & 7)) << 4));
      }
#pragma unroll
      for (int nf = 0; nf < BNF; ++nf) {
        int r = wc + nf * 16 + lr;
        int g = kkk * 4 + lg;
        bf[nf] = *(const short8*)((const char*)Bs + r * 128 + ((g ^ (r & 7)) << 4));
      }
#pragma unroll
      for (int mf = 0; mf < 4; ++mf)
#pragma unroll
        for (int nf = 0; nf < BNF; ++nf)
          acc[mf][nf] = mfma16(af[mf], bf[nf], acc[mf][nf]);
    }
    __syncthreads();
  }

  const int colbase = bn * BN + wc;
  float bv[BNF];
#pragma unroll
  for (int nf = 0; nf < BNF; ++nf) bv[nf] = bias[colbase + nf * 16 + lr];

  if constexpr (EPI == 0) {
    if (bn < 16) {
      // Q / K scatter epilogue (tile wholly Q (bn<8) or K (bn<16): 768 = 8*96)
#pragma unroll
      for (int nf = 0; nf < BNF; ++nf) {
        int col = colbase + nf * 16 + lr;
        int which = col / 768;
        int rem = col - which * 768;
        int h = rem >> 6, d = rem & 63;
#pragma unroll
        for (int mf = 0; mf < 4; ++mf) {
#pragma unroll
          for (int j = 0; j < 4; ++j) {
            int row = bm * 128 + wr + mf * 16 + lg * 4 + j;
            int bb = row >> 11, nn = row & 2047;
            float v = acc[mf][nf][j] + bv[nf];
            size_t off = (((size_t)bb * 12 + h) * 2048 + nn) * 64 + d;
            if (which == 0)
              qo[off] = f2bf(v * (0.125f * LOG2E));  // fold 1/sqrt(64) and log2e into Q
            else
              ko[off] = f2bf(v);
          }
        }
      }
    } else {
      // V: two 48-col LDS-transpose passes -> vt[B,H,64,2048], eb-scaled,
      // coalesced 64B/thread stores. smem reused as lt[48][132] (12.7KB).
      unsigned short* lt = smem;
      const int vcolbase = bn * BN - 1536;  // 0,96,...,672
      const int token0 = bm * 128;          // whole block in one batch
      const int bb = token0 >> 11;
      const int nnb = token0 & 2047;
#pragma unroll
      for (int p = 0; p < 2; ++p) {
        __syncthreads();  // staging/previous-pass reads complete
        if ((wid & 1) == p) {
#pragma unroll
          for (int nf = 0; nf < BNF; ++nf) {
            int c = nf * 16 + lr;  // pass-local col 0..47
#pragma unroll
            for (int mf = 0; mf < 4; ++mf)
#pragma unroll
              for (int j = 0; j < 4; ++j) {
                int r = wr + mf * 16 + lg * 4 + j;
                lt[c * 132 + r] = f2bf(acc[mf][nf][j] + bv[nf]);
              }
          }
        }
        __syncthreads();
        // write out: threads 0..191 -> (c = tid>>2, 32 tokens at r0=(tid&3)*32)
        if (tid < 192) {
          int c = tid >> 2, r0 = (tid & 3) * 32;
          int vcol = vcolbase + p * 48 + c;  // 0..767
          int h = vcol >> 6, d = vcol & 63;
          unsigned short* dstp = vo + (((size_t)bb * 12 + h) * 64 + d) * 2048 + nnb + r0;
          const unsigned short* ebp = ebb + bb * 2048 + nnb + r0;
#pragma unroll
          for (int k = 0; k < 4; ++k) {
            short8 vv = *(const short8*)(lt + c * 132 + r0 + k * 8);
            short8 ebv = *(const short8*)(ebp + k * 8);
            short8 outv;
#pragma unroll
            for (int e = 0; e < 8; ++e)
              outv[e] = (short)f2bf(bf2f((unsigned short)vv[e]) * bf2f((unsigned short)ebv[e]));
            *(short8*)(dstp + k * 8) = outv;
          }
        }
      }
    }
  } else {
#pragma unroll
    for (int mf = 0; mf < 4; ++mf) {
#pragma unroll
      for (int j = 0; j < 4; ++j) {
        int row = bm * 128 + wr + mf * 16 + lg * 4 + j;
#pragma unroll
        for (int nf = 0; nf < BNF; ++nf) {
          int col = colbase + nf * 16 + lr;
          outf[(size_t)row * 768 + col] = acc[mf][nf][j] + bv[nf];
        }
      }
    }
  }
}

// --------------------------- flash attention -------------------------------
// grid (16 qblocks, 48 heads), 256 thr. Per block: 128 q-rows, 4 waves x 32 rows.
// Swapped QK^T (S^T = mfma(K_slot, Q)), kappa1 key permutation -> PV A-frag
// packed in-register (no P LDS). Bias folded into V/eb. K/V LDS dbuf,
// 1 barrier/iter; loop unrolled x2 (literal buffer index); hoisted offsets.
// R15: peeled kkk=0 with loop-invariant zero C-in (no per-tile s zero-movs).
__global__ __launch_bounds__(256, 3) void attn_fused(
    const unsigned short* __restrict__ Q, const unsigned short* __restrict__ Kx,
    const unsigned short* __restrict__ Vt, const unsigned short* __restrict__ ebb,
    unsigned short* __restrict__ Ao) {
  __shared__ __align__(16) unsigned short Ks[2][64 * 64];
  __shared__ __align__(16) unsigned short Vs[2][64 * 64];
  const int tid = threadIdx.x, lane = tid & 63, wid = tid >> 6;
  const int lr = lane & 15, lg = lane >> 4;
  const int qb = blockIdx.x, bh = blockIdx.y;
  const int b = bh / 12, h = bh - b * 12;
  const size_t hoff = (size_t)bh * (2048 * 64);
  const unsigned short* Qh = Q + hoff;
  const unsigned short* Kh = Kx + hoff;
  const unsigned short* Vh = Vt + hoff;        // [64][2048], pre-scaled by eb
  const unsigned short* ebh = ebb + b * 2048;  // bf16 exp(bias), natural order

  // Q fragments (held whole kernel)
  short8 qf[2][2];
#pragma unroll
  for (int mf = 0; mf < 2; ++mf)
#pragma unroll
    for (int kkk = 0; kkk < 2; ++kkk) {
      int qr = qb * 128 + wid * 32 + mf * 16 + lr;
      qf[mf][kkk] = *(const short8*)(Qh + (size_t)qr * 64 + kkk * 32 + lg * 8);
    }

  const int c0 = wid * 2, c1 = wid * 2 + 1;
  const int r0s = c0 * 8 + (lane >> 3), r1s = c1 * 8 + (lane >> 3);
  const int g0 = (lane & 7) ^ (r0s & 7), g1 = (lane & 7) ^ (r1s & 7);
  const int k1r0 = kappa1(r0s), k1r1 = kappa1(r1s);  // K source-row permutation

  // hoisted swizzled LDS read byte-offsets (loop-invariant)
  unsigned koff[2][4], voff[2][4];
#pragma unroll
  for (int kkk = 0; kkk < 2; ++kkk)
#pragma unroll
    for (int nf = 0; nf < 4; ++nf) {
      int r = nf * 16 + lr, g = kkk * 4 + lg;
      koff[kkk][nf] = (unsigned)(r * 128 + ((g ^ (r & 7)) << 4));
      voff[kkk][nf] = koff[kkk][nf];
    }

  f32x4 o[2][4] = {};
  f32x4 ol[2] = {};  // l accumulator via MFMA (all cols identical)
  const f32x4 fzero = {0.f, 0.f, 0.f, 0.f};  // loop-invariant MFMA C-in

#define STAGE(buf, t)                                                                  \
  do {                                                                                 \
    const int kt0_ = (t) * 64;                                                         \
    gload_lds16(Kh + (size_t)(kt0_ + k1r0) * 64 + g0 * 8, (char*)Ks[buf] + c0 * 1024); \
    gload_lds16(Kh + (size_t)(kt0_ + k1r1) * 64 + g1 * 8, (char*)Ks[buf] + c1 * 1024); \
    gload_lds16(Vh + (size_t)r0s * 2048 + kt0_ + g0 * 8, (char*)Vs[buf] + c0 * 1024);  \
    gload_lds16(Vh + (size_t)r1s * 2048 + kt0_ + g1 * 8, (char*)Vs[buf] + c1 * 1024);  \
  } while (0)

  // BODY(buf, kt0): buf literal -> LDS addrs fold; kkk=0 peeled with fzero C-in
#define BODY(buf, kt0)                                                                 \
  do {                                                                                 \
    short8 ebf[2];                                                                     \
    _Pragma("unroll") for (int kkk = 0; kkk < 2; ++kkk)                                \
        ebf[kkk] = *(const short8*)(ebh + (kt0) + kkk * 32 + lg * 8);                  \
    short8 kf0[4], kf1[4];                                                             \
    _Pragma("unroll") for (int nf = 0; nf < 4; ++nf) {                                 \
      kf0[nf] = *(const short8*)((const char*)Ks[buf] + koff[0][nf]);                  \
      kf1[nf] = *(const short8*)((const char*)Ks[buf] + koff[1][nf]);                  \
    }                                                                                  \
    f32x4 s[4][2];                                                                     \
    _Pragma("unroll") for (int nf = 0; nf < 4; ++nf)                                   \
        _Pragma("unroll") for (int mf = 0; mf < 2; ++mf)                               \
            s[nf][mf] = mfma16(kf0[nf], qf[mf][0], fzero);                             \
    _Pragma("unroll") for (int nf = 0; nf < 4; ++nf)                                   \
        _Pragma("unroll") for (int mf = 0; mf < 2; ++mf)                               \
            s[nf][mf] = mfma16(kf1[nf], qf[mf][1], s[nf][mf]);                         \
    _Pragma("unroll") for (int nf = 0; nf < 4; ++nf)                                   \
        _Pragma("unroll") for (int mf = 0; mf < 2; ++mf)                               \
            _Pragma("unroll") for (int j = 0; j < 4; ++j)                              \
                s[nf][mf][j] = __builtin_exp2f(s[nf][mf][j]);                          \
    short8 pa[2][2];                                                                   \
    _Pragma("unroll") for (int mf = 0; mf < 2; ++mf)                                   \
        _Pragma("unroll") for (int kkk = 0; kkk < 2; ++kkk) {                          \
      u32x4 w;                                                                         \
      w[0] = cvt_pk_bf16(s[kkk][mf][0], s[kkk][mf][1]);                                \
      w[1] = cvt_pk_bf16(s[kkk][mf][2], s[kkk][mf][3]);                                \
      w[2] = cvt_pk_bf16(s[kkk + 2][mf][0], s[kkk + 2][mf][1]);                        \
      w[3] = cvt_pk_bf16(s[kkk + 2][mf][2], s[kkk + 2][mf][3]);                        \
      pa[mf][kkk] = __builtin_bit_cast(short8, w);                                     \
    }                                                                                  \
    _Pragma("unroll") for (int kkk = 0; kkk < 2; ++kkk) {                              \
      short8 vf[4];                                                                    \
      _Pragma("unroll") for (int nf = 0; nf < 4; ++nf)                                 \
          vf[nf] = *(const short8*)((const char*)Vs[buf] + voff[kkk][nf]);             \
      _Pragma("unroll") for (int mf = 0; mf < 2; ++mf) {                               \
        ol[mf] = mfma16(pa[mf][kkk], ebf[kkk], ol[mf]);                                \
        _Pragma("unroll") for (int nf = 0; nf < 4; ++nf)                               \
            o[mf][nf] = mfma16(pa[mf][kkk], vf[nf], o[mf][nf]);                        \
      }                                                                                \
    }                                                                                  \
  } while (0)

  STAGE(0, 0);

  for (int t = 0; t < 32; t += 2) {
    __syncthreads();  // K/V[0] landed (staged a full phase ago); [1] free
    STAGE(1, t + 1);
    BODY(0, t * 64);
    __syncthreads();  // K/V[1] landed; [0] free
    if (t + 2 < 32) STAGE(0, t + 2);
    BODY(1, (t + 1) * 64);
  }
#undef STAGE
#undef BODY

  // epilogue: O / l -> bf16 -> attn_out [B][N][C]; l is in O-frag layout.
#pragma unroll
  for (int mf = 0; mf < 2; ++mf)
#pragma unroll
    for (int j = 0; j < 4; ++j) {
      float inv = 1.f / ol[mf][j];
      int qr = qb * 128 + wid * 32 + mf * 16 + lg * 4 + j;
#pragma unroll
      for (int nf = 0; nf < 4; ++nf) {
        int d = nf * 16 + lr;
        Ao[((size_t)b * 2048 + qr) * 768 + h * 64 + d] = f2bf(o[mf][nf][j] * inv);
      }
    }
}

// ------------------------------ launcher -----------------------------------

extern "C" void kernel_launch(void* const* d_in, const int* in_sizes, int n_in,
                              void* d_out, int out_size, void* d_ws, size_t ws_size,
                              hipStream_t stream) {
  (void)in_sizes; (void)n_in; (void)out_size; (void)ws_size;
  const float* x = (const float*)d_in[0];
  const float* wqkv = (const float*)d_in[1];
  const float* bqkv = (const float*)d_in[2];
  const float* wproj = (const float*)d_in[3];
  const float* bproj = (const float*)d_in[4];
  const float* klb = (const float*)d_in[5];
  float* out = (float*)d_out;
  char* ws = (char*)d_ws;

  const size_t SZ = (size_t)8192 * 768 * 2;  // 12,582,912 B (one [B,N,C] bf16)
  unsigned short* xb = (unsigned short*)(ws);
  unsigned short* wqkvT = (unsigned short*)(ws + SZ);
  unsigned short* wprojT = (unsigned short*)(ws + SZ + 3538944);
  unsigned short* qbuf = (unsigned short*)(ws + SZ + 3538944 + 1179648);
  unsigned short* kbuf = (unsigned short*)(ws + SZ + 3538944 + 1179648 + SZ);
  unsigned short* vtbuf = (unsigned short*)(ws + SZ + 3538944 + 1179648 + 2 * SZ);
  unsigned short* ebb = (unsigned short*)(ws + SZ + 3538944 + 1179648 + 3 * SZ);
  unsigned short* aob = xb;  // xb dead after gemm1; reuse for attention output

  // one fused prep dispatch: x->bf16 | exp(bias) | wqkv^T | wproj^T
  prep<<<dim3(5408), dim3(256), 0, stream>>>(x, xb, klb, ebb, wqkv, wqkvT,
                                             wproj, wprojT);
  // qkv GEMM (BN=96, 1536 blocks = 2 exact rounds, XCD-swizzled 1D grid)
  gemm_bt<0, 3, 24><<<dim3(1536), dim3(256), 0, stream>>>(xb, wqkvT, bqkv, nullptr,
                                                          qbuf, kbuf, vtbuf, ebb, 768);
  attn_fused<<<dim3(16, 48), dim3(256), 0, stream>>>(qbuf, kbuf, vtbuf, ebb, aob);
  // proj GEMM (BN=64, 768 blocks = 1 exact round, XCD-swizzled 1D grid)
  gemm_bt<1, 2, 12><<<dim3(768), dim3(256), 0, stream>>>(aob, wprojT, bproj, out,
                                                         nullptr, nullptr, nullptr,
                                                         nullptr, 768);
}

// Round 16
// 136.842 us; speedup vs baseline: 1.0225x; 1.0225x over previous
//
#include <hip/hip_runtime.h>

// ---------------------------------------------------------------------------
// Fused attention block: qkv = x@Wqkv+b; per-head softmax(q k^T/8 + keybias) v;
// out = attn@Wproj+b.  B=4 N=2048 C=768 H=12 HD=64.
// Internal compute bf16 MFMA (16x16x32), fp32 accumulate.
// R16: best-of-both cleanup — R14's GEMMs (2D grid, NO XCD swizzle; swizzle
// was wrong-regime for L3-resident operands, cost +2.3us) + R15's attn
// (fzero-peeled QK^T, -1us). No new mechanisms.
// ---------------------------------------------------------------------------

typedef short short8 __attribute__((ext_vector_type(8)));
typedef float f32x4 __attribute__((ext_vector_type(4)));
typedef unsigned int u32x4 __attribute__((ext_vector_type(4)));

#define GLB_AS(p) ((const __attribute__((address_space(1))) void*)(p))
#define LDS_AS(p) ((__attribute__((address_space(3))) void*)(p))

__device__ __forceinline__ void gload_lds16(const void* g, void* l) {
  // dest = wave-uniform LDS base + lane*16 (m97 fast path)
  __builtin_amdgcn_global_load_lds(GLB_AS(g), LDS_AS(l), 16, 0, 0);
}

__device__ __forceinline__ f32x4 mfma16(short8 a, short8 b, f32x4 c) {
  return __builtin_amdgcn_mfma_f32_16x16x32_bf16(a, b, c, 0, 0, 0);
}

__device__ __forceinline__ unsigned short f2bf(float f) {
  union { float f; unsigned u; } v; v.f = f;
  unsigned r = v.u + 0x7fffu + ((v.u >> 16) & 1u);
  return (unsigned short)(r >> 16);
}

__device__ __forceinline__ float bf2f(unsigned short u) {
  union { unsigned u; float f; } v; v.u = ((unsigned)u) << 16;
  return v.f;
}

// packed f32x2 -> bf16x2 (lo = a, hi = b)
__device__ __forceinline__ unsigned cvt_pk_bf16(float a, float b) {
  unsigned r;
  asm("v_cvt_pk_bf16_f32 %0, %1, %2" : "=v"(r) : "v"(a), "v"(b));
  return r;
}

#define LOG2E 1.44269504088896340736f

// key-slot permutation: S^T slot m holds original key kappa1(m).
// kappa1(m) = 32*m4 + 8*((m>>2)&3) + 4*m5 + (m&3)  (bijective on 0..63)
__device__ __forceinline__ int kappa1(int m) {
  return ((m >> 4) & 1) * 32 + ((m >> 2) & 3) * 8 + ((m >> 5) & 1) * 4 + (m & 3);
}

// --------------------------- fused prep kernel ------------------------------
// blocks [0,3072):      x f32 -> bf16 (8 elems/thread)
// blocks [3072,3104):   ebb = bf16(exp(klb))
// blocks [3104,4832):   wqkv^T (f32 [768][2304] -> bf16 [2304][768])
// blocks [4832,5408):   wproj^T (f32 [768][768] -> bf16 [768][768])
__global__ __launch_bounds__(256) void prep(
    const float* __restrict__ x, unsigned short* __restrict__ xb,
    const float* __restrict__ klb, unsigned short* __restrict__ ebb,
    const float* __restrict__ wqkv, unsigned short* __restrict__ wqkvT,
    const float* __restrict__ wproj, unsigned short* __restrict__ wprojT) {
  const int bid = blockIdx.x, tid = threadIdx.x;
  if (bid < 3072) {
    int i = bid * 256 + tid;
    const float4* p = (const float4*)x + 2 * (size_t)i;
    float4 a = p[0], c = p[1];
    short8 r;
    r[0] = (short)f2bf(a.x); r[1] = (short)f2bf(a.y); r[2] = (short)f2bf(a.z); r[3] = (short)f2bf(a.w);
    r[4] = (short)f2bf(c.x); r[5] = (short)f2bf(c.y); r[6] = (short)f2bf(c.z); r[7] = (short)f2bf(c.w);
    ((short8*)xb)[i] = r;
    return;
  }
  if (bid < 3104) {
    int i = (bid - 3072) * 256 + tid;
    ebb[i] = f2bf(__builtin_exp2f(klb[i] * LOG2E));
    return;
  }
  // transpose+convert branches (block-uniform; LDS tile + barrier ok)
  __shared__ float t[32][33];
  const float* src;
  unsigned short* dst;
  int R, C, bx, by;
  if (bid < 4832) {
    int i = bid - 3104;
    src = wqkv; dst = wqkvT; R = 768; C = 2304; bx = i % 72; by = i / 72;
  } else {
    int i = bid - 4832;
    src = wproj; dst = wprojT; R = 768; C = 768; bx = i % 24; by = i / 24;
  }
  int tx = tid & 31, ty = tid >> 5;
  int c0 = bx * 32, r0 = by * 32;
#pragma unroll
  for (int i = 0; i < 32; i += 8)
    t[ty + i][tx] = src[(size_t)(r0 + ty + i) * C + c0 + tx];
  __syncthreads();
#pragma unroll
  for (int i = 0; i < 32; i += 8)
    dst[(size_t)(c0 + ty + i) * R + r0 + tx] = f2bf(t[tx][ty + i]);
}

// ------------------------------- GEMM --------------------------------------
// C[M,N] = A[M,K] * Bt[N,K]^T, 128xBN tile (BN = 32*BNF), BK=64, 4 waves (2x2),
// m97 structure, 3 blocks/CU, plain 2D grid (no swizzle).
// EPI=0 (BNF=3, BN=96): qkv epilogue — bn<16: Q (x0.125*log2e) / K scatter;
//        bn>=16: V transpose-through-LDS, write V^T*eb coalesced.
// EPI=1 (BNF=2, BN=64): proj epilogue (bias, fp32 out [M][768])
template <int EPI, int BNF>
__global__ __launch_bounds__(256, 3) void gemm_bt(
    const unsigned short* __restrict__ A, const unsigned short* __restrict__ Bt,
    const float* __restrict__ bias, float* __restrict__ outf,
    unsigned short* __restrict__ qo, unsigned short* __restrict__ ko,
    unsigned short* __restrict__ vo, const unsigned short* __restrict__ ebb,
    int K) {
  constexpr int BN = BNF * 32;
  __shared__ __align__(16) unsigned short smem[128 * 64 + BN * 64];
  unsigned short* As = smem;
  unsigned short* Bs = smem + 128 * 64;
  const int tid = threadIdx.x;
  const int lane = tid & 63, wid = tid >> 6;
  const int lr = lane & 15, lg = lane >> 4;
  const int bm = blockIdx.x, bn = blockIdx.y;
  const int wr = (wid >> 1) * 64, wc = (wid & 1) * (BNF * 16);

  const unsigned short* ap[4];
  unsigned aoff[4];
#pragma unroll
  for (int i = 0; i < 4; ++i) {
    int c = wid * 4 + i;
    int r = c * 8 + (lane >> 3);
    int gs = (lane & 7) ^ (r & 7);
    ap[i] = A + (size_t)(bm * 128 + r) * K + gs * 8;
    aoff[i] = (unsigned)c * 1024;
  }
  const unsigned short* bp[BNF];
  unsigned boff[BNF];
#pragma unroll
  for (int i = 0; i < BNF; ++i) {
    int c = wid * BNF + i;
    int r = c * 8 + (lane >> 3);
    int gs = (lane & 7) ^ (r & 7);
    bp[i] = Bt + (size_t)(bn * BN + r) * K + gs * 8;
    boff[i] = (unsigned)c * 1024;
  }

  f32x4 acc[4][BNF] = {};
  const int nt = K >> 6;
  for (int t = 0; t < nt; ++t) {
#pragma unroll
    for (int i = 0; i < 4; ++i) {
      gload_lds16(ap[i], (char*)As + aoff[i]);
      ap[i] += 64;
    }
#pragma unroll
    for (int i = 0; i < BNF; ++i) {
      gload_lds16(bp[i], (char*)Bs + boff[i]);
      bp[i] += 64;
    }
    __syncthreads();
#pragma unroll
    for (int kkk = 0; kkk < 2; ++kkk) {
      short8 af[4], bf[BNF];
#pragma unroll
      for (int mf = 0; mf < 4; ++mf) {
        int r = wr + mf * 16 + lr;
        int g = kkk * 4 + lg;
        af[mf] = *(const short8*)((const char*)As + r * 128 + ((g ^ (r & 7)) << 4));
      }
#pragma unroll
      for (int nf = 0; nf < BNF; ++nf) {
        int r = wc + nf * 16 + lr;
        int g = kkk * 4 + lg;
        bf[nf] = *(const short8*)((const char*)Bs + r * 128 + ((g ^ (r & 7)) << 4));
      }
#pragma unroll
      for (int mf = 0; mf < 4; ++mf)
#pragma unroll
        for (int nf = 0; nf < BNF; ++nf)
          acc[mf][nf] = mfma16(af[mf], bf[nf], acc[mf][nf]);
    }
    __syncthreads();
  }

  const int colbase = bn * BN + wc;
  float bv[BNF];
#pragma unroll
  for (int nf = 0; nf < BNF; ++nf) bv[nf] = bias[colbase + nf * 16 + lr];

  if constexpr (EPI == 0) {
    if (bn < 16) {
      // Q / K scatter epilogue (tile wholly Q (bn<8) or K (bn<16): 768 = 8*96)
#pragma unroll
      for (int nf = 0; nf < BNF; ++nf) {
        int col = colbase + nf * 16 + lr;
        int which = col / 768;
        int rem = col - which * 768;
        int h = rem >> 6, d = rem & 63;
#pragma unroll
        for (int mf = 0; mf < 4; ++mf) {
#pragma unroll
          for (int j = 0; j < 4; ++j) {
            int row = bm * 128 + wr + mf * 16 + lg * 4 + j;
            int bb = row >> 11, nn = row & 2047;
            float v = acc[mf][nf][j] + bv[nf];
            size_t off = (((size_t)bb * 12 + h) * 2048 + nn) * 64 + d;
            if (which == 0)
              qo[off] = f2bf(v * (0.125f * LOG2E));  // fold 1/sqrt(64) and log2e into Q
            else
              ko[off] = f2bf(v);
          }
        }
      }
    } else {
      // V: two 48-col LDS-transpose passes -> vt[B,H,64,2048], eb-scaled,
      // coalesced 64B/thread stores. smem reused as lt[48][132] (12.7KB).
      unsigned short* lt = smem;
      const int vcolbase = bn * BN - 1536;  // 0,96,...,672
      const int token0 = bm * 128;          // whole block in one batch
      const int bb = token0 >> 11;
      const int nnb = token0 & 2047;
#pragma unroll
      for (int p = 0; p < 2; ++p) {
        __syncthreads();  // staging/previous-pass reads complete
        if ((wid & 1) == p) {
#pragma unroll
          for (int nf = 0; nf < BNF; ++nf) {
            int c = nf * 16 + lr;  // pass-local col 0..47
#pragma unroll
            for (int mf = 0; mf < 4; ++mf)
#pragma unroll
              for (int j = 0; j < 4; ++j) {
                int r = wr + mf * 16 + lg * 4 + j;
                lt[c * 132 + r] = f2bf(acc[mf][nf][j] + bv[nf]);
              }
          }
        }
        __syncthreads();
        // write out: threads 0..191 -> (c = tid>>2, 32 tokens at r0=(tid&3)*32)
        if (tid < 192) {
          int c = tid >> 2, r0 = (tid & 3) * 32;
          int vcol = vcolbase + p * 48 + c;  // 0..767
          int h = vcol >> 6, d = vcol & 63;
          unsigned short* dstp = vo + (((size_t)bb * 12 + h) * 64 + d) * 2048 + nnb + r0;
          const unsigned short* ebp = ebb + bb * 2048 + nnb + r0;
#pragma unroll
          for (int k = 0; k < 4; ++k) {
            short8 vv = *(const short8*)(lt + c * 132 + r0 + k * 8);
            short8 ebv = *(const short8*)(ebp + k * 8);
            short8 outv;
#pragma unroll
            for (int e = 0; e < 8; ++e)
              outv[e] = (short)f2bf(bf2f((unsigned short)vv[e]) * bf2f((unsigned short)ebv[e]));
            *(short8*)(dstp + k * 8) = outv;
          }
        }
      }
    }
  } else {
#pragma unroll
    for (int mf = 0; mf < 4; ++mf) {
#pragma unroll
      for (int j = 0; j < 4; ++j) {
        int row = bm * 128 + wr + mf * 16 + lg * 4 + j;
#pragma unroll
        for (int nf = 0; nf < BNF; ++nf) {
          int col = colbase + nf * 16 + lr;
          outf[(size_t)row * 768 + col] = acc[mf][nf][j] + bv[nf];
        }
      }
    }
  }
}

// --------------------------- flash attention -------------------------------
// grid (16 qblocks, 48 heads), 256 thr. Per block: 128 q-rows, 4 waves x 32 rows.
// Swapped QK^T (S^T = mfma(K_slot, Q)), kappa1 key permutation -> PV A-frag
// packed in-register (no P LDS). Bias folded into V/eb. K/V LDS dbuf,
// 1 barrier/iter; loop unrolled x2 (literal buffer index); hoisted offsets;
// peeled kkk=0 with loop-invariant zero C-in.  [R15 verbatim]
__global__ __launch_bounds__(256, 3) void attn_fused(
    const unsigned short* __restrict__ Q, const unsigned short* __restrict__ Kx,
    const unsigned short* __restrict__ Vt, const unsigned short* __restrict__ ebb,
    unsigned short* __restrict__ Ao) {
  __shared__ __align__(16) unsigned short Ks[2][64 * 64];
  __shared__ __align__(16) unsigned short Vs[2][64 * 64];
  const int tid = threadIdx.x, lane = tid & 63, wid = tid >> 6;
  const int lr = lane & 15, lg = lane >> 4;
  const int qb = blockIdx.x, bh = blockIdx.y;
  const int b = bh / 12, h = bh - b * 12;
  const size_t hoff = (size_t)bh * (2048 * 64);
  const unsigned short* Qh = Q + hoff;
  const unsigned short* Kh = Kx + hoff;
  const unsigned short* Vh = Vt + hoff;        // [64][2048], pre-scaled by eb
  const unsigned short* ebh = ebb + b * 2048;  // bf16 exp(bias), natural order

  // Q fragments (held whole kernel)
  short8 qf[2][2];
#pragma unroll
  for (int mf = 0; mf < 2; ++mf)
#pragma unroll
    for (int kkk = 0; kkk < 2; ++kkk) {
      int qr = qb * 128 + wid * 32 + mf * 16 + lr;
      qf[mf][kkk] = *(const short8*)(Qh + (size_t)qr * 64 + kkk * 32 + lg * 8);
    }

  const int c0 = wid * 2, c1 = wid * 2 + 1;
  const int r0s = c0 * 8 + (lane >> 3), r1s = c1 * 8 + (lane >> 3);
  const int g0 = (lane & 7) ^ (r0s & 7), g1 = (lane & 7) ^ (r1s & 7);
  const int k1r0 = kappa1(r0s), k1r1 = kappa1(r1s);  // K source-row permutation

  // hoisted swizzled LDS read byte-offsets (loop-invariant)
  unsigned koff[2][4], voff[2][4];
#pragma unroll
  for (int kkk = 0; kkk < 2; ++kkk)
#pragma unroll
    for (int nf = 0; nf < 4; ++nf) {
      int r = nf * 16 + lr, g = kkk * 4 + lg;
      koff[kkk][nf] = (unsigned)(r * 128 + ((g ^ (r & 7)) << 4));
      voff[kkk][nf] = koff[kkk][nf];
    }

  f32x4 o[2][4] = {};
  f32x4 ol[2] = {};  // l accumulator via MFMA (all cols identical)
  const f32x4 fzero = {0.f, 0.f, 0.f, 0.f};  // loop-invariant MFMA C-in

#define STAGE(buf, t)                                                                  \
  do {                                                                                 \
    const int kt0_ = (t) * 64;                                                         \
    gload_lds16(Kh + (size_t)(kt0_ + k1r0) * 64 + g0 * 8, (char*)Ks[buf] + c0 * 1024); \
    gload_lds16(Kh + (size_t)(kt0_ + k1r1) * 64 + g1 * 8, (char*)Ks[buf] + c1 * 1024); \
    gload_lds16(Vh + (size_t)r0s * 2048 + kt0_ + g0 * 8, (char*)Vs[buf] + c0 * 1024);  \
    gload_lds16(Vh + (size_t)r1s * 2048 + kt0_ + g1 * 8, (char*)Vs[buf] + c1 * 1024);  \
  } while (0)

  // BODY(buf, kt0): buf literal -> LDS addrs fold; kkk=0 peeled with fzero C-in
#define BODY(buf, kt0)                                                                 \
  do {                                                                                 \
    short8 ebf[2];                                                                     \
    _Pragma("unroll") for (int kkk = 0; kkk < 2; ++kkk)                                \
        ebf[kkk] = *(const short8*)(ebh + (kt0) + kkk * 32 + lg * 8);                  \
    short8 kf0[4], kf1[4];                                                             \
    _Pragma("unroll") for (int nf = 0; nf < 4; ++nf) {                                 \
      kf0[nf] = *(const short8*)((const char*)Ks[buf] + koff[0][nf]);                  \
      kf1[nf] = *(const short8*)((const char*)Ks[buf] + koff[1][nf]);                  \
    }                                                                                  \
    f32x4 s[4][2];                                                                     \
    _Pragma("unroll") for (int nf = 0; nf < 4; ++nf)                                   \
        _Pragma("unroll") for (int mf = 0; mf < 2; ++mf)                               \
            s[nf][mf] = mfma16(kf0[nf], qf[mf][0], fzero);                             \
    _Pragma("unroll") for (int nf = 0; nf < 4; ++nf)                                   \
        _Pragma("unroll") for (int mf = 0; mf < 2; ++mf)                               \
            s[nf][mf] = mfma16(kf1[nf], qf[mf][1], s[nf][mf]);                         \
    _Pragma("unroll") for (int nf = 0; nf < 4; ++nf)                                   \
        _Pragma("unroll") for (int mf = 0; mf < 2; ++mf)                               \
            _Pragma("unroll") for (int j = 0; j < 4; ++j)                              \
                s[nf][mf][j] = __builtin_exp2f(s[nf][mf][j]);                          \
    short8 pa[2][2];                                                                   \
    _Pragma("unroll") for (int mf = 0; mf < 2; ++mf)                                   \
        _Pragma("unroll") for (int kkk = 0; kkk < 2; ++kkk) {                          \
      u32x4 w;                                                                         \
      w[0] = cvt_pk_bf16(s[kkk][mf][0], s[kkk][mf][1]);                                \
      w[1] = cvt_pk_bf16(s[kkk][mf][2], s[kkk][mf][3]);                                \
      w[2] = cvt_pk_bf16(s[kkk + 2][mf][0], s[kkk + 2][mf][1]);                        \
      w[3] = cvt_pk_bf16(s[kkk + 2][mf][2], s[kkk + 2][mf][3]);                        \
      pa[mf][kkk] = __builtin_bit_cast(short8, w);                                     \
    }                                                                                  \
    _Pragma("unroll") for (int kkk = 0; kkk < 2; ++kkk) {                              \
      short8 vf[4];                                                                    \
      _Pragma("unroll") for (int nf = 0; nf < 4; ++nf)                                 \
          vf[nf] = *(const short8*)((const char*)Vs[buf] + voff[kkk][nf]);             \
      _Pragma("unroll") for (int mf = 0; mf < 2; ++mf) {                               \
        ol[mf] = mfma16(pa[mf][kkk], ebf[kkk], ol[mf]);                                \
        _Pragma("unroll") for (int nf = 0; nf < 4; ++nf)                               \
            o[mf][nf] = mfma16(pa[mf][kkk], vf[nf], o[mf][nf]);                        \
      }                                                                                \
    }                                                                                  \
  } while (0)

  STAGE(0, 0);

  for (int t = 0; t < 32; t += 2) {
    __syncthreads();  // K/V[0] landed (staged a full phase ago); [1] free
    STAGE(1, t + 1);
    BODY(0, t * 64);
    __syncthreads();  // K/V[1] landed; [0] free
    if (t + 2 < 32) STAGE(0, t + 2);
    BODY(1, (t + 1) * 64);
  }
#undef STAGE
#undef BODY

  // epilogue: O / l -> bf16 -> attn_out [B][N][C]; l is in O-frag layout.
#pragma unroll
  for (int mf = 0; mf < 2; ++mf)
#pragma unroll
    for (int j = 0; j < 4; ++j) {
      float inv = 1.f / ol[mf][j];
      int qr = qb * 128 + wid * 32 + mf * 16 + lg * 4 + j;
#pragma unroll
      for (int nf = 0; nf < 4; ++nf) {
        int d = nf * 16 + lr;
        Ao[((size_t)b * 2048 + qr) * 768 + h * 64 + d] = f2bf(o[mf][nf][j] * inv);
      }
    }
}

// ------------------------------ launcher -----------------------------------

extern "C" void kernel_launch(void* const* d_in, const int* in_sizes, int n_in,
                              void* d_out, int out_size, void* d_ws, size_t ws_size,
                              hipStream_t stream) {
  (void)in_sizes; (void)n_in; (void)out_size; (void)ws_size;
  const float* x = (const float*)d_in[0];
  const float* wqkv = (const float*)d_in[1];
  const float* bqkv = (const float*)d_in[2];
  const float* wproj = (const float*)d_in[3];
  const float* bproj = (const float*)d_in[4];
  const float* klb = (const float*)d_in[5];
  float* out = (float*)d_out;
  char* ws = (char*)d_ws;

  const size_t SZ = (size_t)8192 * 768 * 2;  // 12,582,912 B (one [B,N,C] bf16)
  unsigned short* xb = (unsigned short*)(ws);
  unsigned short* wqkvT = (unsigned short*)(ws + SZ);
  unsigned short* wprojT = (unsigned short*)(ws + SZ + 3538944);
  unsigned short* qbuf = (unsigned short*)(ws + SZ + 3538944 + 1179648);
  unsigned short* kbuf = (unsigned short*)(ws + SZ + 3538944 + 1179648 + SZ);
  unsigned short* vtbuf = (unsigned short*)(ws + SZ + 3538944 + 1179648 + 2 * SZ);
  unsigned short* ebb = (unsigned short*)(ws + SZ + 3538944 + 1179648 + 3 * SZ);
  unsigned short* aob = xb;  // xb dead after gemm1; reuse for attention output

  // one fused prep dispatch: x->bf16 | exp(bias) | wqkv^T | wproj^T
  prep<<<dim3(5408), dim3(256), 0, stream>>>(x, xb, klb, ebb, wqkv, wqkvT,
                                             wproj, wprojT);
  // qkv GEMM (BN=96, 1536 blocks = 2 exact rounds); V^T+eb in-epilogue
  gemm_bt<0, 3><<<dim3(64, 24), dim3(256), 0, stream>>>(xb, wqkvT, bqkv, nullptr,
                                                        qbuf, kbuf, vtbuf, ebb, 768);
  attn_fused<<<dim3(16, 48), dim3(256), 0, stream>>>(qbuf, kbuf, vtbuf, ebb, aob);
  // proj GEMM (BN=64, 768 blocks = 1 exact round)
  gemm_bt<1, 2><<<dim3(64, 12), dim3(256), 0, stream>>>(aob, wprojT, bproj, out,
                                                        nullptr, nullptr, nullptr,
                                                        nullptr, 768);
}

// Round 17
// 135.348 us; speedup vs baseline: 1.0337x; 1.0110x over previous
//
#include <hip/hip_runtime.h>

// ---------------------------------------------------------------------------
// Fused attention block: qkv = x@Wqkv+b; per-head softmax(q k^T/8 + keybias) v;
// out = attn@Wproj+b.  B=4 N=2048 C=768 H=12 HD=64.
// Internal compute bf16 MFMA (16x16x32), fp32 accumulate.
// R17: attn STAGE/eb addresses carried as incrementing pointers (constant
// per-tile strides; kills per-tile 64-bit address recomputation — the GEMM
// ap[i]+=64 idiom applied to attn). Else R16 verbatim.
// ---------------------------------------------------------------------------

typedef short short8 __attribute__((ext_vector_type(8)));
typedef float f32x4 __attribute__((ext_vector_type(4)));
typedef unsigned int u32x4 __attribute__((ext_vector_type(4)));

#define GLB_AS(p) ((const __attribute__((address_space(1))) void*)(p))
#define LDS_AS(p) ((__attribute__((address_space(3))) void*)(p))

__device__ __forceinline__ void gload_lds16(const void* g, void* l) {
  // dest = wave-uniform LDS base + lane*16 (m97 fast path)
  __builtin_amdgcn_global_load_lds(GLB_AS(g), LDS_AS(l), 16, 0, 0);
}

__device__ __forceinline__ f32x4 mfma16(short8 a, short8 b, f32x4 c) {
  return __builtin_amdgcn_mfma_f32_16x16x32_bf16(a, b, c, 0, 0, 0);
}

__device__ __forceinline__ unsigned short f2bf(float f) {
  union { float f; unsigned u; } v; v.f = f;
  unsigned r = v.u + 0x7fffu + ((v.u >> 16) & 1u);
  return (unsigned short)(r >> 16);
}

__device__ __forceinline__ float bf2f(unsigned short u) {
  union { unsigned u; float f; } v; v.u = ((unsigned)u) << 16;
  return v.f;
}

// packed f32x2 -> bf16x2 (lo = a, hi = b)
__device__ __forceinline__ unsigned cvt_pk_bf16(float a, float b) {
  unsigned r;
  asm("v_cvt_pk_bf16_f32 %0, %1, %2" : "=v"(r) : "v"(a), "v"(b));
  return r;
}

#define LOG2E 1.44269504088896340736f

// key-slot permutation: S^T slot m holds original key kappa1(m).
// kappa1(m) = 32*m4 + 8*((m>>2)&3) + 4*m5 + (m&3)  (bijective on 0..63)
__device__ __forceinline__ int kappa1(int m) {
  return ((m >> 4) & 1) * 32 + ((m >> 2) & 3) * 8 + ((m >> 5) & 1) * 4 + (m & 3);
}

// --------------------------- fused prep kernel ------------------------------
// blocks [0,3072):      x f32 -> bf16 (8 elems/thread)
// blocks [3072,3104):   ebb = bf16(exp(klb))
// blocks [3104,4832):   wqkv^T (f32 [768][2304] -> bf16 [2304][768])
// blocks [4832,5408):   wproj^T (f32 [768][768] -> bf16 [768][768])
__global__ __launch_bounds__(256) void prep(
    const float* __restrict__ x, unsigned short* __restrict__ xb,
    const float* __restrict__ klb, unsigned short* __restrict__ ebb,
    const float* __restrict__ wqkv, unsigned short* __restrict__ wqkvT,
    const float* __restrict__ wproj, unsigned short* __restrict__ wprojT) {
  const int bid = blockIdx.x, tid = threadIdx.x;
  if (bid < 3072) {
    int i = bid * 256 + tid;
    const float4* p = (const float4*)x + 2 * (size_t)i;
    float4 a = p[0], c = p[1];
    short8 r;
    r[0] = (short)f2bf(a.x); r[1] = (short)f2bf(a.y); r[2] = (short)f2bf(a.z); r[3] = (short)f2bf(a.w);
    r[4] = (short)f2bf(c.x); r[5] = (short)f2bf(c.y); r[6] = (short)f2bf(c.z); r[7] = (short)f2bf(c.w);
    ((short8*)xb)[i] = r;
    return;
  }
  if (bid < 3104) {
    int i = (bid - 3072) * 256 + tid;
    ebb[i] = f2bf(__builtin_exp2f(klb[i] * LOG2E));
    return;
  }
  // transpose+convert branches (block-uniform; LDS tile + barrier ok)
  __shared__ float t[32][33];
  const float* src;
  unsigned short* dst;
  int R, C, bx, by;
  if (bid < 4832) {
    int i = bid - 3104;
    src = wqkv; dst = wqkvT; R = 768; C = 2304; bx = i % 72; by = i / 72;
  } else {
    int i = bid - 4832;
    src = wproj; dst = wprojT; R = 768; C = 768; bx = i % 24; by = i / 24;
  }
  int tx = tid & 31, ty = tid >> 5;
  int c0 = bx * 32, r0 = by * 32;
#pragma unroll
  for (int i = 0; i < 32; i += 8)
    t[ty + i][tx] = src[(size_t)(r0 + ty + i) * C + c0 + tx];
  __syncthreads();
#pragma unroll
  for (int i = 0; i < 32; i += 8)
    dst[(size_t)(c0 + ty + i) * R + r0 + tx] = f2bf(t[tx][ty + i]);
}

// ------------------------------- GEMM --------------------------------------
// C[M,N] = A[M,K] * Bt[N,K]^T, 128xBN tile (BN = 32*BNF), BK=64, 4 waves (2x2),
// m97 structure, 3 blocks/CU, plain 2D grid (no swizzle).
// EPI=0 (BNF=3, BN=96): qkv epilogue — bn<16: Q (x0.125*log2e) / K scatter;
//        bn>=16: V transpose-through-LDS, write V^T*eb coalesced.
// EPI=1 (BNF=2, BN=64): proj epilogue (bias, fp32 out [M][768])
template <int EPI, int BNF>
__global__ __launch_bounds__(256, 3) void gemm_bt(
    const unsigned short* __restrict__ A, const unsigned short* __restrict__ Bt,
    const float* __restrict__ bias, float* __restrict__ outf,
    unsigned short* __restrict__ qo, unsigned short* __restrict__ ko,
    unsigned short* __restrict__ vo, const unsigned short* __restrict__ ebb,
    int K) {
  constexpr int BN = BNF * 32;
  __shared__ __align__(16) unsigned short smem[128 * 64 + BN * 64];
  unsigned short* As = smem;
  unsigned short* Bs = smem + 128 * 64;
  const int tid = threadIdx.x;
  const int lane = tid & 63, wid = tid >> 6;
  const int lr = lane & 15, lg = lane >> 4;
  const int bm = blockIdx.x, bn = blockIdx.y;
  const int wr = (wid >> 1) * 64, wc = (wid & 1) * (BNF * 16);

  const unsigned short* ap[4];
  unsigned aoff[4];
#pragma unroll
  for (int i = 0; i < 4; ++i) {
    int c = wid * 4 + i;
    int r = c * 8 + (lane >> 3);
    int gs = (lane & 7) ^ (r & 7);
    ap[i] = A + (size_t)(bm * 128 + r) * K + gs * 8;
    aoff[i] = (unsigned)c * 1024;
  }
  const unsigned short* bp[BNF];
  unsigned boff[BNF];
#pragma unroll
  for (int i = 0; i < BNF; ++i) {
    int c = wid * BNF + i;
    int r = c * 8 + (lane >> 3);
    int gs = (lane & 7) ^ (r & 7);
    bp[i] = Bt + (size_t)(bn * BN + r) * K + gs * 8;
    boff[i] = (unsigned)c * 1024;
  }

  f32x4 acc[4][BNF] = {};
  const int nt = K >> 6;
  for (int t = 0; t < nt; ++t) {
#pragma unroll
    for (int i = 0; i < 4; ++i) {
      gload_lds16(ap[i], (char*)As + aoff[i]);
      ap[i] += 64;
    }
#pragma unroll
    for (int i = 0; i < BNF; ++i) {
      gload_lds16(bp[i], (char*)Bs + boff[i]);
      bp[i] += 64;
    }
    __syncthreads();
#pragma unroll
    for (int kkk = 0; kkk < 2; ++kkk) {
      short8 af[4], bf[BNF];
#pragma unroll
      for (int mf = 0; mf < 4; ++mf) {
        int r = wr + mf * 16 + lr;
        int g = kkk * 4 + lg;
        af[mf] = *(const short8*)((const char*)As + r * 128 + ((g ^ (r & 7)) << 4));
      }
#pragma unroll
      for (int nf = 0; nf < BNF; ++nf) {
        int r = wc + nf * 16 + lr;
        int g = kkk * 4 + lg;
        bf[nf] = *(const short8*)((const char*)Bs + r * 128 + ((g ^ (r & 7)) << 4));
      }
#pragma unroll
      for (int mf = 0; mf < 4; ++mf)
#pragma unroll
        for (int nf = 0; nf < BNF; ++nf)
          acc[mf][nf] = mfma16(af[mf], bf[nf], acc[mf][nf]);
    }
    __syncthreads();
  }

  const int colbase = bn * BN + wc;
  float bv[BNF];
#pragma unroll
  for (int nf = 0; nf < BNF; ++nf) bv[nf] = bias[colbase + nf * 16 + lr];

  if constexpr (EPI == 0) {
    if (bn < 16) {
      // Q / K scatter epilogue (tile wholly Q (bn<8) or K (bn<16): 768 = 8*96)
#pragma unroll
      for (int nf = 0; nf < BNF; ++nf) {
        int col = colbase + nf * 16 + lr;
        int which = col / 768;
        int rem = col - which * 768;
        int h = rem >> 6, d = rem & 63;
#pragma unroll
        for (int mf = 0; mf < 4; ++mf) {
#pragma unroll
          for (int j = 0; j < 4; ++j) {
            int row = bm * 128 + wr + mf * 16 + lg * 4 + j;
            int bb = row >> 11, nn = row & 2047;
            float v = acc[mf][nf][j] + bv[nf];
            size_t off = (((size_t)bb * 12 + h) * 2048 + nn) * 64 + d;
            if (which == 0)
              qo[off] = f2bf(v * (0.125f * LOG2E));  // fold 1/sqrt(64) and log2e into Q
            else
              ko[off] = f2bf(v);
          }
        }
      }
    } else {
      // V: two 48-col LDS-transpose passes -> vt[B,H,64,2048], eb-scaled,
      // coalesced 64B/thread stores. smem reused as lt[48][132] (12.7KB).
      unsigned short* lt = smem;
      const int vcolbase = bn * BN - 1536;  // 0,96,...,672
      const int token0 = bm * 128;          // whole block in one batch
      const int bb = token0 >> 11;
      const int nnb = token0 & 2047;
#pragma unroll
      for (int p = 0; p < 2; ++p) {
        __syncthreads();  // staging/previous-pass reads complete
        if ((wid & 1) == p) {
#pragma unroll
          for (int nf = 0; nf < BNF; ++nf) {
            int c = nf * 16 + lr;  // pass-local col 0..47
#pragma unroll
            for (int mf = 0; mf < 4; ++mf)
#pragma unroll
              for (int j = 0; j < 4; ++j) {
                int r = wr + mf * 16 + lg * 4 + j;
                lt[c * 132 + r] = f2bf(acc[mf][nf][j] + bv[nf]);
              }
          }
        }
        __syncthreads();
        // write out: threads 0..191 -> (c = tid>>2, 32 tokens at r0=(tid&3)*32)
        if (tid < 192) {
          int c = tid >> 2, r0 = (tid & 3) * 32;
          int vcol = vcolbase + p * 48 + c;  // 0..767
          int h = vcol >> 6, d = vcol & 63;
          unsigned short* dstp = vo + (((size_t)bb * 12 + h) * 64 + d) * 2048 + nnb + r0;
          const unsigned short* ebp = ebb + bb * 2048 + nnb + r0;
#pragma unroll
          for (int k = 0; k < 4; ++k) {
            short8 vv = *(const short8*)(lt + c * 132 + r0 + k * 8);
            short8 ebv = *(const short8*)(ebp + k * 8);
            short8 outv;
#pragma unroll
            for (int e = 0; e < 8; ++e)
              outv[e] = (short)f2bf(bf2f((unsigned short)vv[e]) * bf2f((unsigned short)ebv[e]));
            *(short8*)(dstp + k * 8) = outv;
          }
        }
      }
    }
  } else {
#pragma unroll
    for (int mf = 0; mf < 4; ++mf) {
#pragma unroll
      for (int j = 0; j < 4; ++j) {
        int row = bm * 128 + wr + mf * 16 + lg * 4 + j;
#pragma unroll
        for (int nf = 0; nf < BNF; ++nf) {
          int col = colbase + nf * 16 + lr;
          outf[(size_t)row * 768 + col] = acc[mf][nf][j] + bv[nf];
        }
      }
    }
  }
}

// --------------------------- flash attention -------------------------------
// grid (16 qblocks, 48 heads), 256 thr. Per block: 128 q-rows, 4 waves x 32 rows.
// Swapped QK^T (S^T = mfma(K_slot, Q)), kappa1 key permutation -> PV A-frag
// packed in-register (no P LDS). Bias folded into V/eb. K/V LDS dbuf,
// 1 barrier/iter; loop unrolled x2 (literal buffer index); hoisted offsets;
// peeled kkk=0 with fzero C-in. R17: stage/eb addresses carried as
// incrementing pointers (constant strides: K 4096, V 64, eb 64 elems/tile).
__global__ __launch_bounds__(256, 3) void attn_fused(
    const unsigned short* __restrict__ Q, const unsigned short* __restrict__ Kx,
    const unsigned short* __restrict__ Vt, const unsigned short* __restrict__ ebb,
    unsigned short* __restrict__ Ao) {
  __shared__ __align__(16) unsigned short Ks[2][64 * 64];
  __shared__ __align__(16) unsigned short Vs[2][64 * 64];
  const int tid = threadIdx.x, lane = tid & 63, wid = tid >> 6;
  const int lr = lane & 15, lg = lane >> 4;
  const int qb = blockIdx.x, bh = blockIdx.y;
  const int b = bh / 12, h = bh - b * 12;
  const size_t hoff = (size_t)bh * (2048 * 64);
  const unsigned short* Qh = Q + hoff;
  const unsigned short* Kh = Kx + hoff;
  const unsigned short* Vh = Vt + hoff;        // [64][2048], pre-scaled by eb
  const unsigned short* ebh = ebb + b * 2048;  // bf16 exp(bias), natural order

  // Q fragments (held whole kernel)
  short8 qf[2][2];
#pragma unroll
  for (int mf = 0; mf < 2; ++mf)
#pragma unroll
    for (int kkk = 0; kkk < 2; ++kkk) {
      int qr = qb * 128 + wid * 32 + mf * 16 + lr;
      qf[mf][kkk] = *(const short8*)(Qh + (size_t)qr * 64 + kkk * 32 + lg * 8);
    }

  const int c0 = wid * 2, c1 = wid * 2 + 1;
  const int r0s = c0 * 8 + (lane >> 3), r1s = c1 * 8 + (lane >> 3);
  const int g0 = (lane & 7) ^ (r0s & 7), g1 = (lane & 7) ^ (r1s & 7);
  const int k1r0 = kappa1(r0s), k1r1 = kappa1(r1s);  // K source-row permutation

  // incrementing stage pointers (strides: K rows advance 64/tile -> 4096 elems;
  // V cols advance 64/tile; eb advances 64/tile)
  const unsigned short* kS0 = Kh + (size_t)k1r0 * 64 + g0 * 8;
  const unsigned short* kS1 = Kh + (size_t)k1r1 * 64 + g1 * 8;
  const unsigned short* vS0 = Vh + (size_t)r0s * 2048 + g0 * 8;
  const unsigned short* vS1 = Vh + (size_t)r1s * 2048 + g1 * 8;
  const unsigned short* ebq = ebh + lg * 8;

  // hoisted swizzled LDS read byte-offsets (loop-invariant)
  unsigned koff[2][4], voff[2][4];
#pragma unroll
  for (int kkk = 0; kkk < 2; ++kkk)
#pragma unroll
    for (int nf = 0; nf < 4; ++nf) {
      int r = nf * 16 + lr, g = kkk * 4 + lg;
      koff[kkk][nf] = (unsigned)(r * 128 + ((g ^ (r & 7)) << 4));
      voff[kkk][nf] = koff[kkk][nf];
    }

  f32x4 o[2][4] = {};
  f32x4 ol[2] = {};  // l accumulator via MFMA (all cols identical)
  const f32x4 fzero = {0.f, 0.f, 0.f, 0.f};  // loop-invariant MFMA C-in

  // STAGE uses current pointers, then advances them by one tile
#define STAGE(buf)                                           \
  do {                                                       \
    gload_lds16(kS0, (char*)Ks[buf] + c0 * 1024);            \
    gload_lds16(kS1, (char*)Ks[buf] + c1 * 1024);            \
    gload_lds16(vS0, (char*)Vs[buf] + c0 * 1024);            \
    gload_lds16(vS1, (char*)Vs[buf] + c1 * 1024);            \
    kS0 += 4096; kS1 += 4096; vS0 += 64; vS1 += 64;          \
  } while (0)

  // BODY(buf): buf literal -> LDS addrs fold; eb via incrementing pointer
#define BODY(buf)                                                                      \
  do {                                                                                 \
    short8 ebf[2];                                                                     \
    ebf[0] = *(const short8*)(ebq);                                                    \
    ebf[1] = *(const short8*)(ebq + 32);                                               \
    ebq += 64;                                                                         \
    short8 kf0[4], kf1[4];                                                             \
    _Pragma("unroll") for (int nf = 0; nf < 4; ++nf) {                                 \
      kf0[nf] = *(const short8*)((const char*)Ks[buf] + koff[0][nf]);                  \
      kf1[nf] = *(const short8*)((const char*)Ks[buf] + koff[1][nf]);                  \
    }                                                                                  \
    f32x4 s[4][2];                                                                     \
    _Pragma("unroll") for (int nf = 0; nf < 4; ++nf)                                   \
        _Pragma("unroll") for (int mf = 0; mf < 2; ++mf)                               \
            s[nf][mf] = mfma16(kf0[nf], qf[mf][0], fzero);                             \
    _Pragma("unroll") for (int nf = 0; nf < 4; ++nf)                                   \
        _Pragma("unroll") for (int mf = 0; mf < 2; ++mf)                               \
            s[nf][mf] = mfma16(kf1[nf], qf[mf][1], s[nf][mf]);                         \
    _Pragma("unroll") for (int nf = 0; nf < 4; ++nf)                                   \
        _Pragma("unroll") for (int mf = 0; mf < 2; ++mf)                               \
            _Pragma("unroll") for (int j = 0; j < 4; ++j)                              \
                s[nf][mf][j] = __builtin_exp2f(s[nf][mf][j]);                          \
    short8 pa[2][2];                                                                   \
    _Pragma("unroll") for (int mf = 0; mf < 2; ++mf)                                   \
        _Pragma("unroll") for (int kkk = 0; kkk < 2; ++kkk) {                          \
      u32x4 w;                                                                         \
      w[0] = cvt_pk_bf16(s[kkk][mf][0], s[kkk][mf][1]);                                \
      w[1] = cvt_pk_bf16(s[kkk][mf][2], s[kkk][mf][3]);                                \
      w[2] = cvt_pk_bf16(s[kkk + 2][mf][0], s[kkk + 2][mf][1]);                        \
      w[3] = cvt_pk_bf16(s[kkk + 2][mf][2], s[kkk + 2][mf][3]);                        \
      pa[mf][kkk] = __builtin_bit_cast(short8, w);                                     \
    }                                                                                  \
    _Pragma("unroll") for (int kkk = 0; kkk < 2; ++kkk) {                              \
      short8 vf[4];                                                                    \
      _Pragma("unroll") for (int nf = 0; nf < 4; ++nf)                                 \
          vf[nf] = *(const short8*)((const char*)Vs[buf] + voff[kkk][nf]);             \
      _Pragma("unroll") for (int mf = 0; mf < 2; ++mf) {                               \
        ol[mf] = mfma16(pa[mf][kkk], ebf[kkk], ol[mf]);                                \
        _Pragma("unroll") for (int nf = 0; nf < 4; ++nf)                               \
            o[mf][nf] = mfma16(pa[mf][kkk], vf[nf], o[mf][nf]);                        \
      }                                                                                \
    }                                                                                  \
  } while (0)

  STAGE(0);  // tile 0

  for (int t = 0; t < 32; t += 2) {
    __syncthreads();  // K/V[0] landed (staged a full phase ago); [1] free
    STAGE(1);         // tile t+1
    BODY(0);          // tile t
    __syncthreads();  // K/V[1] landed; [0] free
    if (t + 2 < 32) STAGE(0);  // tile t+2
    BODY(1);          // tile t+1
  }
#undef STAGE
#undef BODY

  // epilogue: O / l -> bf16 -> attn_out [B][N][C]; l is in O-frag layout.
#pragma unroll
  for (int mf = 0; mf < 2; ++mf)
#pragma unroll
    for (int j = 0; j < 4; ++j) {
      float inv = 1.f / ol[mf][j];
      int qr = qb * 128 + wid * 32 + mf * 16 + lg * 4 + j;
#pragma unroll
      for (int nf = 0; nf < 4; ++nf) {
        int d = nf * 16 + lr;
        Ao[((size_t)b * 2048 + qr) * 768 + h * 64 + d] = f2bf(o[mf][nf][j] * inv);
      }
    }
}

// ------------------------------ launcher -----------------------------------

extern "C" void kernel_launch(void* const* d_in, const int* in_sizes, int n_in,
                              void* d_out, int out_size, void* d_ws, size_t ws_size,
                              hipStream_t stream) {
  (void)in_sizes; (void)n_in; (void)out_size; (void)ws_size;
  const float* x = (const float*)d_in[0];
  const float* wqkv = (const float*)d_in[1];
  const float* bqkv = (const float*)d_in[2];
  const float* wproj = (const float*)d_in[3];
  const float* bproj = (const float*)d_in[4];
  const float* klb = (const float*)d_in[5];
  float* out = (float*)d_out;
  char* ws = (char*)d_ws;

  const size_t SZ = (size_t)8192 * 768 * 2;  // 12,582,912 B (one [B,N,C] bf16)
  unsigned short* xb = (unsigned short*)(ws);
  unsigned short* wqkvT = (unsigned short*)(ws + SZ);
  unsigned short* wprojT = (unsigned short*)(ws + SZ + 3538944);
  unsigned short* qbuf = (unsigned short*)(ws + SZ + 3538944 + 1179648);
  unsigned short* kbuf = (unsigned short*)(ws + SZ + 3538944 + 1179648 + SZ);
  unsigned short* vtbuf = (unsigned short*)(ws + SZ + 3538944 + 1179648 + 2 * SZ);
  unsigned short* ebb = (unsigned short*)(ws + SZ + 3538944 + 1179648 + 3 * SZ);
  unsigned short* aob = xb;  // xb dead after gemm1; reuse for attention output

  // one fused prep dispatch: x->bf16 | exp(bias) | wqkv^T | wproj^T
  prep<<<dim3(5408), dim3(256), 0, stream>>>(x, xb, klb, ebb, wqkv, wqkvT,
                                             wproj, wprojT);
  // qkv GEMM (BN=96, 1536 blocks = 2 exact rounds); V^T+eb in-epilogue
  gemm_bt<0, 3><<<dim3(64, 24), dim3(256), 0, stream>>>(xb, wqkvT, bqkv, nullptr,
                                                        qbuf, kbuf, vtbuf, ebb, 768);
  attn_fused<<<dim3(16, 48), dim3(256), 0, stream>>>(qbuf, kbuf, vtbuf, ebb, aob);
  // proj GEMM (BN=64, 768 blocks = 1 exact round)
  gemm_bt<1, 2><<<dim3(64, 12), dim3(256), 0, stream>>>(aob, wprojT, bproj, out,
                                                        nullptr, nullptr, nullptr,
                                                        nullptr, 768);
}